// Round 1
// baseline (538.699 us; speedup 1.0000x reference)
//
#include <hip/hip_runtime.h>

typedef unsigned long long u64;
typedef unsigned int u32;

#define N0 147456   // 384*384
#define N1 36864    // 192*192
#define NTOT 184320 // = 720 * 256 exactly
#define KKP 512
#define KM 128
#define CAP_CAND 16384
#define NBINS 16384
#define CAP_COL 2048

struct InPtrs {
  const float* rep[2][2];   // [img][level]
  const float* rel[2][2];
  const float* desc[2][2];
};

// ---------------- candidate generation ----------------
// slot = img*2 + b. Key = (score_bits<<32) | ~pixel_index  ->  descending sort
// == descending score, ties broken by LOWER index (matches lax.top_k).
// Block-aggregated append: LDS atomics + ONE global atomic per block.
__global__ __launch_bounds__(256) void cand_kernel(InPtrs P, u64* __restrict__ cand,
                                                   int* __restrict__ cnt) {
  __shared__ u64 buf[256];
  __shared__ int lcnt, gbase;
  int slot = blockIdx.y;
  int img = slot >> 1, b = slot & 1;
  int p = blockIdx.x * 256 + threadIdx.x;   // NTOT == 720*256, no tail
  if (threadIdx.x == 0) lcnt = 0;
  __syncthreads();
  int level, W, q, Npix;
  if (p < N0) { level = 0; W = 384; q = p; Npix = N0; }
  else        { level = 1; W = 192; q = p - N0; Npix = N1; }
  const float* rp = P.rep[img][level] + (size_t)b * Npix;
  const float* rl = P.rel[img][level] + (size_t)b * Npix;
  float v = rp[q];
  float m = sqrtf(v * rl[q]);
  bool ok = (m >= 0.7f);
  if (ok) {
    int y = q / W, x = q - y * W;   // square levels: H == W
    int y0 = (y > 0) ? y - 1 : y, y1 = (y < W - 1) ? y + 1 : y;
    int x0 = (x > 0) ? x - 1 : x, x1 = (x < W - 1) ? x + 1 : x;
    for (int yy = y0; yy <= y1 && ok; ++yy)
      for (int xx = x0; xx <= x1; ++xx)
        if (rp[yy * W + xx] > v) { ok = false; break; }
  }
  if (ok) {
    u32 sb = __float_as_uint(m);
    int pos = atomicAdd(&lcnt, 1);          // LDS atomic: cheap, per-CU
    buf[pos] = ((u64)sb << 32) | (u32)(~(u32)p);
  }
  __syncthreads();
  if (threadIdx.x == 0) gbase = lcnt ? atomicAdd(&cnt[slot * 16], lcnt) : 0;
  __syncthreads();
  int n = lcnt;
  if ((int)threadIdx.x < n) {
    int pos = gbase + (int)threadIdx.x;
    if (pos < CAP_CAND) cand[(size_t)slot * CAP_CAND + pos] = buf[threadIdx.x];
  }
}

// ---------------- bitonic sort of 2048 u64 keys in LDS, descending ----------------
__device__ inline void bitonic2048(u64* k, int t) {
  for (int size = 2; size <= 2048; size <<= 1) {
    for (int j = size >> 1; j > 0; j >>= 1) {
      __syncthreads();
      for (int i = t; i < 2048; i += 1024) {
        int ixj = i ^ j;
        if (ixj > i) {
          u64 a = k[i], b = k[ixj];
          bool desc = ((i & size) == 0);
          if (desc ? (a < b) : (a > b)) { k[i] = b; k[ixj] = a; }
        }
      }
    }
  }
  __syncthreads();
}

// ---------------- keypoint top-512: radix-select + exact sort + decode ----------------
__global__ __launch_bounds__(1024) void kp_select(const u64* __restrict__ keys_all,
                                                  const int* __restrict__ cnt,
                                                  float* __restrict__ kp_loc,
                                                  int* __restrict__ kp_level,
                                                  int* __restrict__ kp_p,
                                                  float* __restrict__ kp_score) {
  __shared__ int hist[NBINS];
  __shared__ u64 kbuf[CAP_COL];
  __shared__ int part[1024];
  __shared__ int Bbin, colcnt;
  int slot = blockIdx.x;
  int t = threadIdx.x;
  const u64* keys = keys_all + (size_t)slot * CAP_CAND;
  int n = cnt[slot * 16]; if (n > CAP_CAND) n = CAP_CAND;
  for (int i = t; i < NBINS; i += 1024) hist[i] = 0;
  if (t == 0) { Bbin = 0; colcnt = 0; }
  __syncthreads();
  for (int i = t; i < n; i += 1024) {
    u32 bin = (u32)((keys[i] >> 41) & (NBINS - 1));
    atomicAdd(&hist[bin], 1);
  }
  __syncthreads();
  const int BPT = NBINS / 1024;
  int base = t * BPT;
  int lsum = 0;
  for (int j = 0; j < BPT; ++j) lsum += hist[base + j];
  part[t] = lsum;
  __syncthreads();
  for (int off = 1; off < 1024; off <<= 1) {   // suffix scan
    int v = (t + off < 1024) ? part[t + off] : 0;
    __syncthreads();
    part[t] += v;
    __syncthreads();
  }
  int Sab = part[t] - lsum;   // count strictly above my bin range
  if (Sab < KKP && Sab + lsum >= KKP) {
    int c = Sab;
    for (int j = BPT - 1; j >= 0; --j) {
      c += hist[base + j];
      if (c >= KKP) { Bbin = base + j; break; }
    }
  }
  __syncthreads();
  int Bb = Bbin;
  for (int i = t; i < n; i += 1024) {
    u64 kk = keys[i];
    if ((int)((kk >> 41) & (NBINS - 1)) >= Bb) {
      int pos = atomicAdd(&colcnt, 1);
      if (pos < CAP_COL) kbuf[pos] = kk;
    }
  }
  __syncthreads();
  int nc = colcnt; if (nc > CAP_COL) nc = CAP_COL;
  for (int i = t; i < CAP_COL; i += 1024) if (i >= nc) kbuf[i] = 0;
  __syncthreads();
  bitonic2048(kbuf, t);
  // fused decode (t < 512)
  if (t < KKP) {
    u64 key = kbuf[t];
    float s = __uint_as_float((u32)(key >> 32));
    u32 idx = ~(u32)key;
    int level, p, W, scale;
    if (idx < N0) { level = 0; p = (int)idx; W = 384; scale = 1; }
    else          { level = 1; p = (int)(idx - N0); W = 192; scale = 2; }
    if (p < 0 || p >= (level ? N1 : N0)) { p = 0; s = 0.f; }  // pad guard
    int y = p / W, x = p - y * W;
    kp_loc[(slot * 2 + 0) * KKP + t] = (float)(y * scale);
    kp_loc[(slot * 2 + 1) * KKP + t] = (float)(x * scale);
    kp_level[slot * KKP + t] = level;
    kp_p[slot * KKP + t] = p;
    kp_score[slot * KKP + t] = s;
  }
}

// ---------------- gather descriptors * score (TRANSPOSED out: dAt[slot][c][k]) ----------
// Also zeroes the global match histogram (stream-ordered strictly before gemm's
// atomics) so the launcher's memset shrinks to 1 KB of counters.
__global__ __launch_bounds__(512) void gather_kernel(InPtrs P, const int* __restrict__ kp_level,
                                                     const int* __restrict__ kp_p,
                                                     const float* __restrict__ kp_score,
                                                     float* __restrict__ dAt,
                                                     int* __restrict__ mhist) {
  int slot = blockIdx.y;
  int c = blockIdx.x;       // 0..127 channel
  int k = threadIdx.x;      // 0..511 keypoint
  int gtid = (slot * 128 + c) * 512 + k;   // 0..262143 over the grid
  if (gtid < 2 * NBINS) mhist[gtid] = 0;
  int img = slot >> 1, b = slot & 1;
  int level = kp_level[slot * KKP + k];
  int p = kp_p[slot * KKP + k];
  float s = kp_score[slot * KKP + k];
  const float* dptr = P.desc[img][level];
  size_t HW = level ? N1 : N0;
  float v = dptr[((size_t)b * 128 + c) * HW + p];
  dAt[((size_t)slot * 128 + c) * KKP + k] = v * s;
}

// ---------------- order-preserving float->u32 key ----------------
__device__ inline u32 fkey32(float v) {
  u32 bits = __float_as_uint(v);
  return (bits & 0x80000000u) ? ~bits : (bits | 0x80000000u);
}

// ---------------- fp32 GEMM + fused match-histogram + last-block scan ----------------
// S[b][k][l] = sum_c A_t[c][k]*B_t[c][l]. 64x64 tile / block(16x16), 4x4 acc.
// Epilogue: histogram the 4096 register-resident S values into an LDS hist that
// UNIONs the dead tA/tB storage (69.6 KB >= 64 KB), flush nonzero bins to the
// global hist, then the last-finishing block per batch (device-scope ticket +
// __threadfence release/acquire, Guideline 16 — no ordering assumption, no spin)
// runs the suffix-scan and writes thrB[b]. Replaces mhist+mscan kernels and the
// 2 MB S re-read.
union GemmSmem {
  struct { float tA[128][68]; float tB[128][68]; } g;  // 68 = 64 + 4 pad
  struct { int lh[NBINS]; int part[256]; } h;
};

__global__ __launch_bounds__(256) void gemm_kernel(const float* __restrict__ dAt,
                                                   float* __restrict__ S,
                                                   int* __restrict__ mhist,
                                                   int* __restrict__ thrB,
                                                   int* __restrict__ done) {
  __shared__ GemmSmem sm;
  __shared__ int isLast;
  int b = blockIdx.z;
  const float* A  = dAt + (size_t)b * 128 * KKP;        // slot img0 = b
  const float* Bm = dAt + (size_t)(2 + b) * 128 * KKP;  // slot img1 = 2+b
  int row0 = blockIdx.y * 64, col0 = blockIdx.x * 64;
  int t = threadIdx.y * 16 + threadIdx.x;
  for (int i = t; i < 2048; i += 256) {                 // 128c x 16 float4
    int c = i >> 4, r4 = (i & 15) << 2;
    *(float4*)&sm.g.tA[c][r4] = *(const float4*)&A[c * KKP + row0 + r4];
    *(float4*)&sm.g.tB[c][r4] = *(const float4*)&Bm[c * KKP + col0 + r4];
  }
  __syncthreads();
  float acc[4][4] = {};
  int ra = threadIdx.y * 4, rb = threadIdx.x * 4;
  for (int k = 0; k < 128; ++k) {
    float4 a4 = *(const float4*)&sm.g.tA[k][ra];
    float4 b4 = *(const float4*)&sm.g.tB[k][rb];
    float a[4] = {a4.x, a4.y, a4.z, a4.w};
    float bb[4] = {b4.x, b4.y, b4.z, b4.w};
    for (int i = 0; i < 4; ++i)
      for (int j = 0; j < 4; ++j)
        acc[i][j] += a[i] * bb[j];
  }
  for (int i = 0; i < 4; ++i) {
    float4 v = {acc[i][0], acc[i][1], acc[i][2], acc[i][3]};
    *(float4*)&S[(size_t)b * KKP * KKP + (size_t)(row0 + ra + i) * KKP + (col0 + rb)] = v;
  }
  // ---- fused match histogram (tA/tB dead; overlay LDS hist) ----
  __syncthreads();                          // all waves done reading tA/tB
  for (int i = t; i < NBINS; i += 256) sm.h.lh[i] = 0;
  __syncthreads();
  for (int i = 0; i < 4; ++i)
    for (int j = 0; j < 4; ++j)
      atomicAdd(&sm.h.lh[fkey32(acc[i][j]) >> 18], 1);
  __syncthreads();
  int* gh = mhist + b * NBINS;
  for (int i = t; i < NBINS; i += 256) {
    int v = sm.h.lh[i];
    if (v) atomicAdd(&gh[i], v);
  }
  __threadfence();                          // release: hist atomics visible device-wide
  __syncthreads();
  if (t == 0) isLast = (atomicAdd(&done[b], 1) == (int)(gridDim.x * gridDim.y) - 1);
  __syncthreads();
  if (!isLast) return;
  // ---- last block per batch: suffix-scan select -> thrB[b] ----
  __threadfence();                          // acquire: invalidate stale cached lines
  const int BPT = NBINS / 256;              // 64 bins/thread
  int base = t * BPT;
  int lsum = 0;
  for (int j = 0; j < BPT; ++j) lsum += gh[base + j];
  sm.h.part[t] = lsum;
  __syncthreads();
  for (int off = 1; off < 256; off <<= 1) { // suffix scan over 256 partials
    int v = (t + off < 256) ? sm.h.part[t + off] : 0;
    __syncthreads();
    sm.h.part[t] += v;
    __syncthreads();
  }
  int Sab = sm.h.part[t] - lsum;            // count strictly above my bin range
  if (Sab < KM && Sab + lsum >= KM) {
    int c = Sab;
    for (int j = BPT - 1; j >= 0; --j) {
      c += gh[base + j];
      if (c >= KM) { thrB[b] = base + j; break; }
    }
  }
}

// ---------------- fused collect + sort + output ----------------
// 256 blocks x 1024 threads per batch: threshold-collect with ONE global atomic
// per block; last-finishing block (ticket + fences) loads mcol, exact bitonic
// sort, decodes matches to locations. Replaces mcollect+msort_out kernels.
__global__ __launch_bounds__(1024) void mcollect_out(const float* __restrict__ S,
                                                     const int* __restrict__ thrB,
                                                     u64* __restrict__ mcol,
                                                     int* __restrict__ cnt,
                                                     int* __restrict__ done,
                                                     const float* __restrict__ kp_loc,
                                                     float* __restrict__ out) {
  __shared__ u64 kbuf[CAP_COL];
  __shared__ int lcnt, gbase, isLast;
  int b = blockIdx.y;
  int t = threadIdx.x;
  if (t == 0) lcnt = 0;
  __syncthreads();
  int flat = blockIdx.x * 1024 + t;         // 256*1024 == 262144, no tail
  u32 key32 = fkey32(S[(size_t)b * KKP * KKP + flat]);
  int pos = -1;
  if ((int)(key32 >> 18) >= thrB[b]) pos = atomicAdd(&lcnt, 1);
  __syncthreads();
  if (t == 0) gbase = lcnt ? atomicAdd(&cnt[b * 16], lcnt) : 0;
  __syncthreads();
  if (pos >= 0) {
    int g = gbase + pos;
    if (g < CAP_COL) mcol[(size_t)b * CAP_COL + g] = ((u64)key32 << 32) | (u32)(~(u32)flat);
  }
  __threadfence();                          // release: mcol stores drained + L2 written back
  __syncthreads();
  if (t == 0) isLast = (atomicAdd(&done[2 + b], 1) == (int)gridDim.x - 1);
  __syncthreads();
  if (!isLast) return;
  __threadfence();                          // acquire
  int n = cnt[b * 16]; if (n > CAP_COL) n = CAP_COL;
  for (int i = t; i < CAP_COL; i += 1024)
    kbuf[i] = (i < n) ? mcol[(size_t)b * CAP_COL + i] : 0ULL;
  __syncthreads();
  bitonic2048(kbuf, t);
  if (t < KM) {
    u64 key = kbuf[t];
    u32 flat2 = ~(u32)key;
    int i1 = (int)(flat2 >> 9), i2 = (int)(flat2 & 511);
    if (i1 >= KKP) { i1 = 0; i2 = 0; }  // pad guard (never hit: 262144 finite scores)
    int slot1 = b, slot2 = 2 + b;
    out[(b * 4 + 0) * KM + t] = kp_loc[(slot1 * 2 + 0) * KKP + i1];
    out[(b * 4 + 1) * KM + t] = kp_loc[(slot1 * 2 + 1) * KKP + i1];
    out[(b * 4 + 2) * KM + t] = kp_loc[(slot2 * 2 + 0) * KKP + i2];
    out[(b * 4 + 3) * KM + t] = kp_loc[(slot2 * 2 + 1) * KKP + i2];
  }
}

extern "C" void kernel_launch(void* const* d_in, const int* in_sizes, int n_in,
                              void* d_out, int out_size, void* d_ws, size_t ws_size,
                              hipStream_t stream) {
  (void)in_sizes; (void)n_in; (void)out_size; (void)ws_size;
  InPtrs P;
  P.rep[0][0] = (const float*)d_in[0];  P.rel[0][0] = (const float*)d_in[1];  P.desc[0][0] = (const float*)d_in[2];
  P.rep[0][1] = (const float*)d_in[3];  P.rel[0][1] = (const float*)d_in[4];  P.desc[0][1] = (const float*)d_in[5];
  P.rep[1][0] = (const float*)d_in[6];  P.rel[1][0] = (const float*)d_in[7];  P.desc[1][0] = (const float*)d_in[8];
  P.rep[1][1] = (const float*)d_in[9];  P.rel[1][1] = (const float*)d_in[10]; P.desc[1][1] = (const float*)d_in[11];

  char* ws = (char*)d_ws;
  // counters: each slot's counter on its own 64B cacheline (stride-16 ints)
  int*   cnt_cand  = (int*)(ws + 0);      // cnt_cand[slot*16], 4 slots -> 256B
  int*   cnt_match = (int*)(ws + 256);    // cnt_match[b*16], 2 -> 128B
  int*   thrB      = (int*)(ws + 512);    // 2 ints
  int*   done      = (int*)(ws + 640);    // done[0..1]=gemm tickets, done[2..3]=collect tickets
  int*   mhist     = (int*)(ws + 1024);   // 2*16384*4 = 131072 (zeroed by gather_kernel)
  size_t off = 1024 + (size_t)2 * NBINS * 4;
  u64*   cand    = (u64*)(ws + off);  off += 4ULL * CAP_CAND * 8;
  float* kp_loc  = (float*)(ws + off); off += 4ULL * 2 * KKP * 4;
  int*   kp_level= (int*)(ws + off);  off += 4ULL * KKP * 4;
  int*   kp_p    = (int*)(ws + off);  off += 4ULL * KKP * 4;
  float* kp_score= (float*)(ws + off); off += 4ULL * KKP * 4;
  float* dAt     = (float*)(ws + off); off += 4ULL * KKP * 128 * 4;
  float* S       = (float*)(ws + off); off += 2ULL * KKP * KKP * 4;
  u64*   mcol    = (u64*)(ws + off);  off += 2ULL * CAP_COL * 8;   // ~3.8 MB total

  // zero counters + tickets only (mhist is zeroed inside gather_kernel,
  // strictly stream-ordered before gemm's histogram atomics)
  hipMemsetAsync(d_ws, 0, 1024, stream);

  cand_kernel<<<dim3(NTOT / 256, 4), 256, 0, stream>>>(P, cand, cnt_cand);
  kp_select<<<4, 1024, 0, stream>>>(cand, cnt_cand, kp_loc, kp_level, kp_p, kp_score);
  gather_kernel<<<dim3(128, 4), 512, 0, stream>>>(P, kp_level, kp_p, kp_score, dAt, mhist);
  gemm_kernel<<<dim3(8, 8, 2), dim3(16, 16), 0, stream>>>(dAt, S, mhist, thrB, done);
  mcollect_out<<<dim3(256, 2), 1024, 0, stream>>>(S, thrB, mcol, cnt_match, done, kp_loc, (float*)d_out);
}

// Round 2
// 433.878 us; speedup vs baseline: 1.2416x; 1.2416x over previous
//
#include <hip/hip_runtime.h>

typedef unsigned long long u64;
typedef unsigned int u32;

#define N0 147456   // 384*384
#define N1 36864    // 192*192
#define NTOT 184320 // = 720 * 256 exactly
#define KKP 512
#define KM 128
#define CAP_CAND 16384
#define NBINS 16384
#define CAP_COL 2048

struct InPtrs {
  const float* rep[2][2];   // [img][level]
  const float* rel[2][2];
  const float* desc[2][2];
};

// ---------------- candidate generation ----------------
// slot = img*2 + b. Key = (score_bits<<32) | ~pixel_index  ->  descending sort
// == descending score, ties broken by LOWER index (matches lax.top_k).
// Block-aggregated append: LDS atomics + ONE global atomic per block.
__global__ __launch_bounds__(256) void cand_kernel(InPtrs P, u64* __restrict__ cand,
                                                   int* __restrict__ cnt) {
  __shared__ u64 buf[256];
  __shared__ int lcnt, gbase;
  int slot = blockIdx.y;
  int img = slot >> 1, b = slot & 1;
  int p = blockIdx.x * 256 + threadIdx.x;   // NTOT == 720*256, no tail
  if (threadIdx.x == 0) lcnt = 0;
  __syncthreads();
  int level, W, q, Npix;
  if (p < N0) { level = 0; W = 384; q = p; Npix = N0; }
  else        { level = 1; W = 192; q = p - N0; Npix = N1; }
  const float* rp = P.rep[img][level] + (size_t)b * Npix;
  const float* rl = P.rel[img][level] + (size_t)b * Npix;
  float v = rp[q];
  float m = sqrtf(v * rl[q]);
  bool ok = (m >= 0.7f);
  if (ok) {
    int y = q / W, x = q - y * W;   // square levels: H == W
    int y0 = (y > 0) ? y - 1 : y, y1 = (y < W - 1) ? y + 1 : y;
    int x0 = (x > 0) ? x - 1 : x, x1 = (x < W - 1) ? x + 1 : x;
    for (int yy = y0; yy <= y1 && ok; ++yy)
      for (int xx = x0; xx <= x1; ++xx)
        if (rp[yy * W + xx] > v) { ok = false; break; }
  }
  if (ok) {
    u32 sb = __float_as_uint(m);
    int pos = atomicAdd(&lcnt, 1);          // LDS atomic: cheap, per-CU
    buf[pos] = ((u64)sb << 32) | (u32)(~(u32)p);
  }
  __syncthreads();
  if (threadIdx.x == 0) gbase = lcnt ? atomicAdd(&cnt[slot * 16], lcnt) : 0;
  __syncthreads();
  int n = lcnt;
  if ((int)threadIdx.x < n) {
    int pos = gbase + (int)threadIdx.x;
    if (pos < CAP_CAND) cand[(size_t)slot * CAP_CAND + pos] = buf[threadIdx.x];
  }
}

// ---------------- bitonic sort of 2048 u64 keys in LDS, descending ----------------
__device__ inline void bitonic2048(u64* k, int t) {
  for (int size = 2; size <= 2048; size <<= 1) {
    for (int j = size >> 1; j > 0; j >>= 1) {
      __syncthreads();
      for (int i = t; i < 2048; i += 1024) {
        int ixj = i ^ j;
        if (ixj > i) {
          u64 a = k[i], b = k[ixj];
          bool desc = ((i & size) == 0);
          if (desc ? (a < b) : (a > b)) { k[i] = b; k[ixj] = a; }
        }
      }
    }
  }
  __syncthreads();
}

// ---------------- keypoint top-512: radix-select + exact sort + decode ----------------
__global__ __launch_bounds__(1024) void kp_select(const u64* __restrict__ keys_all,
                                                  const int* __restrict__ cnt,
                                                  float* __restrict__ kp_loc,
                                                  int* __restrict__ kp_level,
                                                  int* __restrict__ kp_p,
                                                  float* __restrict__ kp_score) {
  __shared__ int hist[NBINS];
  __shared__ u64 kbuf[CAP_COL];
  __shared__ int part[1024];
  __shared__ int Bbin, colcnt;
  int slot = blockIdx.x;
  int t = threadIdx.x;
  const u64* keys = keys_all + (size_t)slot * CAP_CAND;
  int n = cnt[slot * 16]; if (n > CAP_CAND) n = CAP_CAND;
  for (int i = t; i < NBINS; i += 1024) hist[i] = 0;
  if (t == 0) { Bbin = 0; colcnt = 0; }
  __syncthreads();
  for (int i = t; i < n; i += 1024) {
    u32 bin = (u32)((keys[i] >> 41) & (NBINS - 1));
    atomicAdd(&hist[bin], 1);
  }
  __syncthreads();
  const int BPT = NBINS / 1024;
  int base = t * BPT;
  int lsum = 0;
  for (int j = 0; j < BPT; ++j) lsum += hist[base + j];
  part[t] = lsum;
  __syncthreads();
  for (int off = 1; off < 1024; off <<= 1) {   // suffix scan
    int v = (t + off < 1024) ? part[t + off] : 0;
    __syncthreads();
    part[t] += v;
    __syncthreads();
  }
  int Sab = part[t] - lsum;   // count strictly above my bin range
  if (Sab < KKP && Sab + lsum >= KKP) {
    int c = Sab;
    for (int j = BPT - 1; j >= 0; --j) {
      c += hist[base + j];
      if (c >= KKP) { Bbin = base + j; break; }
    }
  }
  __syncthreads();
  int Bb = Bbin;
  for (int i = t; i < n; i += 1024) {
    u64 kk = keys[i];
    if ((int)((kk >> 41) & (NBINS - 1)) >= Bb) {
      int pos = atomicAdd(&colcnt, 1);
      if (pos < CAP_COL) kbuf[pos] = kk;
    }
  }
  __syncthreads();
  int nc = colcnt; if (nc > CAP_COL) nc = CAP_COL;
  for (int i = t; i < CAP_COL; i += 1024) if (i >= nc) kbuf[i] = 0;
  __syncthreads();
  bitonic2048(kbuf, t);
  // fused decode (t < 512)
  if (t < KKP) {
    u64 key = kbuf[t];
    float s = __uint_as_float((u32)(key >> 32));
    u32 idx = ~(u32)key;
    int level, p, W, scale;
    if (idx < N0) { level = 0; p = (int)idx; W = 384; scale = 1; }
    else          { level = 1; p = (int)(idx - N0); W = 192; scale = 2; }
    if (p < 0 || p >= (level ? N1 : N0)) { p = 0; s = 0.f; }  // pad guard
    int y = p / W, x = p - y * W;
    kp_loc[(slot * 2 + 0) * KKP + t] = (float)(y * scale);
    kp_loc[(slot * 2 + 1) * KKP + t] = (float)(x * scale);
    kp_level[slot * KKP + t] = level;
    kp_p[slot * KKP + t] = p;
    kp_score[slot * KKP + t] = s;
  }
}

// ---------------- gather descriptors * score (TRANSPOSED out: dAt[slot][c][k]) ----------
// Also zeroes the global match histogram (stream-ordered strictly before gemm's
// atomics) so the launcher's memset covers only 1 KB of counters.
__global__ __launch_bounds__(512) void gather_kernel(InPtrs P, const int* __restrict__ kp_level,
                                                     const int* __restrict__ kp_p,
                                                     const float* __restrict__ kp_score,
                                                     float* __restrict__ dAt,
                                                     int* __restrict__ mhist) {
  int slot = blockIdx.y;
  int c = blockIdx.x;       // 0..127 channel
  int k = threadIdx.x;      // 0..511 keypoint
  int gtid = (slot * 128 + c) * 512 + k;   // 0..262143 over the grid
  if (gtid < 2 * NBINS) mhist[gtid] = 0;
  int img = slot >> 1, b = slot & 1;
  int level = kp_level[slot * KKP + k];
  int p = kp_p[slot * KKP + k];
  float s = kp_score[slot * KKP + k];
  const float* dptr = P.desc[img][level];
  size_t HW = level ? N1 : N0;
  float v = dptr[((size_t)b * 128 + c) * HW + p];
  dAt[((size_t)slot * 128 + c) * KKP + k] = v * s;
}

// ---------------- order-preserving float->u32 key ----------------
__device__ inline u32 fkey32(float v) {
  u32 bits = __float_as_uint(v);
  return (bits & 0x80000000u) ? ~bits : (bits | 0x80000000u);
}

// ---------------- fp32 GEMM + fused match-histogram (NO fences, NO tickets) --------
// S[b][k][l] = sum_c A_t[c][k]*B_t[c][l]. 64x64 tile / block(16x16), 4x4 acc.
// Epilogue histograms the 4096 register-resident S values into an LDS hist that
// UNIONs the dead tA/tB storage, then flushes nonzero bins with global atomics.
// Visibility to the next kernel comes from the stream dependency (kernel
// boundary), NOT per-block __threadfence — R1 post-mortem: 512 device-scope
// fences cost ~100+ us of idle-wave stall on gfx950's non-coherent XCD L2s.
union GemmSmem {
  struct { float tA[128][68]; float tB[128][68]; } g;  // 68 = 64 + 4 pad
  struct { int lh[NBINS]; } h;
};

__global__ __launch_bounds__(256) void gemm_kernel(const float* __restrict__ dAt,
                                                   float* __restrict__ S,
                                                   int* __restrict__ mhist) {
  __shared__ GemmSmem sm;
  int b = blockIdx.z;
  const float* A  = dAt + (size_t)b * 128 * KKP;        // slot img0 = b
  const float* Bm = dAt + (size_t)(2 + b) * 128 * KKP;  // slot img1 = 2+b
  int row0 = blockIdx.y * 64, col0 = blockIdx.x * 64;
  int t = threadIdx.y * 16 + threadIdx.x;
  for (int i = t; i < 2048; i += 256) {                 // 128c x 16 float4
    int c = i >> 4, r4 = (i & 15) << 2;
    *(float4*)&sm.g.tA[c][r4] = *(const float4*)&A[c * KKP + row0 + r4];
    *(float4*)&sm.g.tB[c][r4] = *(const float4*)&Bm[c * KKP + col0 + r4];
  }
  __syncthreads();
  float acc[4][4] = {};
  int ra = threadIdx.y * 4, rb = threadIdx.x * 4;
  for (int k = 0; k < 128; ++k) {
    float4 a4 = *(const float4*)&sm.g.tA[k][ra];
    float4 b4 = *(const float4*)&sm.g.tB[k][rb];
    float a[4] = {a4.x, a4.y, a4.z, a4.w};
    float bb[4] = {b4.x, b4.y, b4.z, b4.w};
    for (int i = 0; i < 4; ++i)
      for (int j = 0; j < 4; ++j)
        acc[i][j] += a[i] * bb[j];
  }
  for (int i = 0; i < 4; ++i) {
    float4 v = {acc[i][0], acc[i][1], acc[i][2], acc[i][3]};
    *(float4*)&S[(size_t)b * KKP * KKP + (size_t)(row0 + ra + i) * KKP + (col0 + rb)] = v;
  }
  // ---- fused match histogram (tA/tB dead; overlay LDS hist) ----
  __syncthreads();                          // all waves done reading tA/tB
  for (int i = t; i < NBINS; i += 256) sm.h.lh[i] = 0;
  __syncthreads();
  for (int i = 0; i < 4; ++i)
    for (int j = 0; j < 4; ++j)
      atomicAdd(&sm.h.lh[fkey32(acc[i][j]) >> 18], 1);
  __syncthreads();
  int* gh = mhist + b * NBINS;
  for (int i = t; i < NBINS; i += 256) {
    int v = sm.h.lh[i];
    if (v) atomicAdd(&gh[i], v);
  }
}

// ---------------- fused match select + collect + sort + output ----------------
// One block per batch (grid=2), 1024 threads. Zero cross-block communication:
// reads the completed global hist (L2-hot, 64 KB), suffix-scans for the top-128
// threshold bin, streams S (1 MB, float4) collecting keys above threshold into
// LDS, then exact bitonic-2048 sort + decode. Replaces mscan+mcollect+msort_out.
__global__ __launch_bounds__(1024) void match_out(const float* __restrict__ S,
                                                  const int* __restrict__ mhist,
                                                  const float* __restrict__ kp_loc,
                                                  float* __restrict__ out) {
  __shared__ u64 kbuf[CAP_COL];
  __shared__ int part[1024];
  __shared__ int Bbin, lcnt;
  int b = blockIdx.x;
  int t = threadIdx.x;
  const int* gh = mhist + b * NBINS;
  if (t == 0) { Bbin = 0; lcnt = 0; }
  const int BPT = NBINS / 1024;   // 16 bins/thread
  int base = t * BPT;
  int lsum = 0;
  for (int j = 0; j < BPT; ++j) lsum += gh[base + j];
  part[t] = lsum;
  __syncthreads();
  for (int off = 1; off < 1024; off <<= 1) {   // suffix scan
    int v = (t + off < 1024) ? part[t + off] : 0;
    __syncthreads();
    part[t] += v;
    __syncthreads();
  }
  int Sab = part[t] - lsum;   // count strictly above my bin range
  if (Sab < KM && Sab + lsum >= KM) {
    int c = Sab;
    for (int j = BPT - 1; j >= 0; --j) {
      c += gh[base + j];
      if (c >= KM) { Bbin = base + j; break; }
    }
  }
  __syncthreads();
  int Bb = Bbin;
  // collect: stream S as float4, append keys above threshold to LDS
  const float4* Sb4 = (const float4*)(S + (size_t)b * KKP * KKP);
  for (int i = t; i < (KKP * KKP) / 4; i += 1024) {
    float4 v = Sb4[i];
    float vv[4] = {v.x, v.y, v.z, v.w};
    for (int c = 0; c < 4; ++c) {
      u32 key32 = fkey32(vv[c]);
      if ((int)(key32 >> 18) >= Bb) {
        int pos = atomicAdd(&lcnt, 1);
        if (pos < CAP_COL) kbuf[pos] = ((u64)key32 << 32) | (u32)(~(u32)(i * 4 + c));
      }
    }
  }
  __syncthreads();
  int nc = lcnt; if (nc > CAP_COL) nc = CAP_COL;
  for (int i = t; i < CAP_COL; i += 1024) if (i >= nc) kbuf[i] = 0;
  __syncthreads();
  bitonic2048(kbuf, t);
  if (t < KM) {
    u64 key = kbuf[t];
    u32 flat = ~(u32)key;
    int i1 = (int)(flat >> 9), i2 = (int)(flat & 511);
    if (i1 >= KKP) { i1 = 0; i2 = 0; }  // pad guard (never hit: 262144 finite scores)
    int slot1 = b, slot2 = 2 + b;
    out[(b * 4 + 0) * KM + t] = kp_loc[(slot1 * 2 + 0) * KKP + i1];
    out[(b * 4 + 1) * KM + t] = kp_loc[(slot1 * 2 + 1) * KKP + i1];
    out[(b * 4 + 2) * KM + t] = kp_loc[(slot2 * 2 + 0) * KKP + i2];
    out[(b * 4 + 3) * KM + t] = kp_loc[(slot2 * 2 + 1) * KKP + i2];
  }
}

extern "C" void kernel_launch(void* const* d_in, const int* in_sizes, int n_in,
                              void* d_out, int out_size, void* d_ws, size_t ws_size,
                              hipStream_t stream) {
  (void)in_sizes; (void)n_in; (void)out_size; (void)ws_size;
  InPtrs P;
  P.rep[0][0] = (const float*)d_in[0];  P.rel[0][0] = (const float*)d_in[1];  P.desc[0][0] = (const float*)d_in[2];
  P.rep[0][1] = (const float*)d_in[3];  P.rel[0][1] = (const float*)d_in[4];  P.desc[0][1] = (const float*)d_in[5];
  P.rep[1][0] = (const float*)d_in[6];  P.rel[1][0] = (const float*)d_in[7];  P.desc[1][0] = (const float*)d_in[8];
  P.rep[1][1] = (const float*)d_in[9];  P.rel[1][1] = (const float*)d_in[10]; P.desc[1][1] = (const float*)d_in[11];

  char* ws = (char*)d_ws;
  // counters: each slot's counter on its own 64B cacheline (stride-16 ints)
  int*   cnt_cand  = (int*)(ws + 0);      // cnt_cand[slot*16], 4 slots -> 256B
  int*   mhist     = (int*)(ws + 1024);   // 2*16384*4 = 131072 (zeroed by gather_kernel)
  size_t off = 1024 + (size_t)2 * NBINS * 4;
  u64*   cand    = (u64*)(ws + off);  off += 4ULL * CAP_CAND * 8;
  float* kp_loc  = (float*)(ws + off); off += 4ULL * 2 * KKP * 4;
  int*   kp_level= (int*)(ws + off);  off += 4ULL * KKP * 4;
  int*   kp_p    = (int*)(ws + off);  off += 4ULL * KKP * 4;
  float* kp_score= (float*)(ws + off); off += 4ULL * KKP * 4;
  float* dAt     = (float*)(ws + off); off += 4ULL * KKP * 128 * 4;
  float* S       = (float*)(ws + off); off += 2ULL * KKP * KKP * 4;   // ~3.8 MB total

  // zero candidate counters only (mhist is zeroed inside gather_kernel,
  // strictly stream-ordered before gemm's histogram atomics)
  hipMemsetAsync(d_ws, 0, 1024, stream);

  cand_kernel<<<dim3(NTOT / 256, 4), 256, 0, stream>>>(P, cand, cnt_cand);
  kp_select<<<4, 1024, 0, stream>>>(cand, cnt_cand, kp_loc, kp_level, kp_p, kp_score);
  gather_kernel<<<dim3(128, 4), 512, 0, stream>>>(P, kp_level, kp_p, kp_score, dAt, mhist);
  gemm_kernel<<<dim3(8, 8, 2), dim3(16, 16), 0, stream>>>(dAt, S, mhist);
  match_out<<<2, 1024, 0, stream>>>(S, mhist, kp_loc, (float*)d_out);
}

// Round 3
// 378.106 us; speedup vs baseline: 1.4247x; 1.1475x over previous
//
#include <hip/hip_runtime.h>

typedef unsigned long long u64;
typedef unsigned int u32;

#define N0 147456   // 384*384
#define N1 36864    // 192*192
#define NTOT 184320 // = 720 * 256 exactly
#define KKP 512
#define KM 128
#define CAP_CAND 16384
#define NBINS 16384
#define CAP_COL 2048
#define BIN12 4096      // gemm block-local histogram bins (key32 >> 20)
#define CAP_MC 32768    // per-batch match-candidate capacity (~9K expected)

struct InPtrs {
  const float* rep[2][2];   // [img][level]
  const float* rel[2][2];
  const float* desc[2][2];
};

// ---------------- candidate generation ----------------
// slot = img*2 + b. Key = (score_bits<<32) | ~pixel_index  ->  descending sort
// == descending score, ties broken by LOWER index (matches lax.top_k).
// Block-aggregated append: LDS atomics + ONE global atomic per block.
__global__ __launch_bounds__(256) void cand_kernel(InPtrs P, u64* __restrict__ cand,
                                                   int* __restrict__ cnt) {
  __shared__ u64 buf[256];
  __shared__ int lcnt, gbase;
  int slot = blockIdx.y;
  int img = slot >> 1, b = slot & 1;
  int p = blockIdx.x * 256 + threadIdx.x;   // NTOT == 720*256, no tail
  if (threadIdx.x == 0) lcnt = 0;
  __syncthreads();
  int level, W, q, Npix;
  if (p < N0) { level = 0; W = 384; q = p; Npix = N0; }
  else        { level = 1; W = 192; q = p - N0; Npix = N1; }
  const float* rp = P.rep[img][level] + (size_t)b * Npix;
  const float* rl = P.rel[img][level] + (size_t)b * Npix;
  float v = rp[q];
  float m = sqrtf(v * rl[q]);
  bool ok = (m >= 0.7f);
  if (ok) {
    int y = q / W, x = q - y * W;   // square levels: H == W
    int y0 = (y > 0) ? y - 1 : y, y1 = (y < W - 1) ? y + 1 : y;
    int x0 = (x > 0) ? x - 1 : x, x1 = (x < W - 1) ? x + 1 : x;
    for (int yy = y0; yy <= y1 && ok; ++yy)
      for (int xx = x0; xx <= x1; ++xx)
        if (rp[yy * W + xx] > v) { ok = false; break; }
  }
  if (ok) {
    u32 sb = __float_as_uint(m);
    int pos = atomicAdd(&lcnt, 1);          // LDS atomic: cheap, per-CU
    buf[pos] = ((u64)sb << 32) | (u32)(~(u32)p);
  }
  __syncthreads();
  if (threadIdx.x == 0) gbase = lcnt ? atomicAdd(&cnt[slot * 16], lcnt) : 0;
  __syncthreads();
  int n = lcnt;
  if ((int)threadIdx.x < n) {
    int pos = gbase + (int)threadIdx.x;
    if (pos < CAP_CAND) cand[(size_t)slot * CAP_CAND + pos] = buf[threadIdx.x];
  }
}

// ------- adaptive bitonic sort of n (pow2) u64 keys in LDS, descending -------
// n is runtime pow2 >= 128; only elements [0,n) are touched. ~40-70% fewer
// passes than fixed-2048 when the collected count is small.
__device__ inline void bitonicN(u64* k, int t, int n, int nthreads) {
  for (int size = 2; size <= n; size <<= 1) {
    for (int j = size >> 1; j > 0; j >>= 1) {
      __syncthreads();
      for (int i = t; i < n; i += nthreads) {
        int ixj = i ^ j;
        if (ixj > i) {
          u64 a = k[i], b = k[ixj];
          bool desc = ((i & size) == 0);
          if (desc ? (a < b) : (a > b)) { k[i] = b; k[ixj] = a; }
        }
      }
    }
  }
  __syncthreads();
}

// ---------------- keypoint top-512: radix-select + exact sort + decode ----------------
__global__ __launch_bounds__(1024) void kp_select(const u64* __restrict__ keys_all,
                                                  const int* __restrict__ cnt,
                                                  float* __restrict__ kp_loc,
                                                  int* __restrict__ kp_level,
                                                  int* __restrict__ kp_p,
                                                  float* __restrict__ kp_score) {
  __shared__ int hist[NBINS];
  __shared__ u64 kbuf[CAP_COL];
  __shared__ int part[1024];
  __shared__ int Bbin, colcnt;
  int slot = blockIdx.x;
  int t = threadIdx.x;
  const u64* keys = keys_all + (size_t)slot * CAP_CAND;
  int n = cnt[slot * 16]; if (n > CAP_CAND) n = CAP_CAND;
  for (int i = t; i < NBINS; i += 1024) hist[i] = 0;
  if (t == 0) { Bbin = 0; colcnt = 0; }
  __syncthreads();
  for (int i = t; i < n; i += 1024) {
    u32 bin = (u32)((keys[i] >> 41) & (NBINS - 1));
    atomicAdd(&hist[bin], 1);
  }
  __syncthreads();
  const int BPT = NBINS / 1024;
  int base = t * BPT;
  int lsum = 0;
  for (int j = 0; j < BPT; ++j) lsum += hist[base + j];
  part[t] = lsum;
  __syncthreads();
  for (int off = 1; off < 1024; off <<= 1) {   // suffix scan
    int v = (t + off < 1024) ? part[t + off] : 0;
    __syncthreads();
    part[t] += v;
    __syncthreads();
  }
  int Sab = part[t] - lsum;   // count strictly above my bin range
  if (Sab < KKP && Sab + lsum >= KKP) {
    int c = Sab;
    for (int j = BPT - 1; j >= 0; --j) {
      c += hist[base + j];
      if (c >= KKP) { Bbin = base + j; break; }
    }
  }
  __syncthreads();
  int Bb = Bbin;
  for (int i = t; i < n; i += 1024) {
    u64 kk = keys[i];
    if ((int)((kk >> 41) & (NBINS - 1)) >= Bb) {
      int pos = atomicAdd(&colcnt, 1);
      if (pos < CAP_COL) kbuf[pos] = kk;
    }
  }
  __syncthreads();
  int nc = colcnt; if (nc > CAP_COL) nc = CAP_COL;   // nc >= 512 by construction
  int npow = 1; while (npow < nc) npow <<= 1;        // adaptive sort width
  for (int i = t; i < npow; i += 1024) if (i >= nc) kbuf[i] = 0;
  __syncthreads();
  bitonicN(kbuf, t, npow, 1024);
  // fused decode (t < 512)
  if (t < KKP) {
    u64 key = kbuf[t];
    float s = __uint_as_float((u32)(key >> 32));
    u32 idx = ~(u32)key;
    int level, p, W, scale;
    if (idx < N0) { level = 0; p = (int)idx; W = 384; scale = 1; }
    else          { level = 1; p = (int)(idx - N0); W = 192; scale = 2; }
    if (p < 0 || p >= (level ? N1 : N0)) { p = 0; s = 0.f; }  // pad guard
    int y = p / W, x = p - y * W;
    kp_loc[(slot * 2 + 0) * KKP + t] = (float)(y * scale);
    kp_loc[(slot * 2 + 1) * KKP + t] = (float)(x * scale);
    kp_level[slot * KKP + t] = level;
    kp_p[slot * KKP + t] = p;
    kp_score[slot * KKP + t] = s;
  }
}

// ---------------- gather descriptors * score (TRANSPOSED out: dAt[slot][c][k]) ----------
__global__ __launch_bounds__(512) void gather_kernel(InPtrs P, const int* __restrict__ kp_level,
                                                     const int* __restrict__ kp_p,
                                                     const float* __restrict__ kp_score,
                                                     float* __restrict__ dAt) {
  int slot = blockIdx.y;
  int c = blockIdx.x;       // 0..127 channel
  int k = threadIdx.x;      // 0..511 keypoint
  int img = slot >> 1, b = slot & 1;
  int level = kp_level[slot * KKP + k];
  int p = kp_p[slot * KKP + k];
  float s = kp_score[slot * KKP + k];
  const float* dptr = P.desc[img][level];
  size_t HW = level ? N1 : N0;
  float v = dptr[((size_t)b * 128 + c) * HW + p];
  dAt[((size_t)slot * 128 + c) * KKP + k] = v * s;
}

// ---------------- order-preserving float->u32 key ----------------
__device__ inline u32 fkey32(float v) {
  u32 bits = __float_as_uint(v);
  return (bits & 0x80000000u) ? ~bits : (bits | 0x80000000u);
}

// ---------------- fp32 GEMM + block-local top-128 candidate select ----------------
// S[b][k][l] = sum_c A_t[c][k]*B_t[c][l]. 64x64 tile / block(16x16), 4x4 acc.
// NO S write, NO global histogram. Each block histograms its own 4096
// register-resident values into a block-LOCAL 4096-bin LDS hist (overlaying the
// dead tA/tB), finds its local top-128 threshold bin, and appends the ~128-200
// qualifying keys with ONE global atomic. Exactness: an element with >=128
// same-block elements in strictly higher bins has >=128 globally-larger keys,
// so the per-block bin-threshold superset contains the global top-128; the
// final select is exact on full keys.
// (R1/R2 post-mortems: per-block device fences ~100us; 400K global hist
// atomics + 2-block 1MB S re-stream ~ +30-40us. Both eliminated here.)
union GemmSmem {
  struct { float tA[128][68]; float tB[128][68]; } g;           // 69,632 B
  struct { int lh[BIN12]; int part[256]; u64 lbuf[4096]; } h;   // 49,408 B
};

__global__ __launch_bounds__(256) void gemm_kernel(const float* __restrict__ dAt,
                                                   u64* __restrict__ mcand,
                                                   int* __restrict__ mcnt) {
  __shared__ GemmSmem sm;
  __shared__ int Bbin, lcnt, gbase;
  int b = blockIdx.z;
  const float* A  = dAt + (size_t)b * 128 * KKP;        // slot img0 = b
  const float* Bm = dAt + (size_t)(2 + b) * 128 * KKP;  // slot img1 = 2+b
  int row0 = blockIdx.y * 64, col0 = blockIdx.x * 64;
  int t = threadIdx.y * 16 + threadIdx.x;
  for (int i = t; i < 2048; i += 256) {                 // 128c x 16 float4
    int c = i >> 4, r4 = (i & 15) << 2;
    *(float4*)&sm.g.tA[c][r4] = *(const float4*)&A[c * KKP + row0 + r4];
    *(float4*)&sm.g.tB[c][r4] = *(const float4*)&Bm[c * KKP + col0 + r4];
  }
  __syncthreads();
  float acc[4][4] = {};
  int ra = threadIdx.y * 4, rb = threadIdx.x * 4;
  for (int k = 0; k < 128; ++k) {
    float4 a4 = *(const float4*)&sm.g.tA[k][ra];
    float4 b4 = *(const float4*)&sm.g.tB[k][rb];
    float a[4] = {a4.x, a4.y, a4.z, a4.w};
    float bb[4] = {b4.x, b4.y, b4.z, b4.w};
    for (int i = 0; i < 4; ++i)
      for (int j = 0; j < 4; ++j)
        acc[i][j] += a[i] * bb[j];
  }
  // ---- block-local select (tA/tB dead; overlay LDS) ----
  __syncthreads();                          // all waves done reading tA/tB
  for (int i = t; i < BIN12; i += 256) sm.h.lh[i] = 0;
  if (t == 0) lcnt = 0;
  __syncthreads();
  u32 k32[4][4];
  for (int i = 0; i < 4; ++i)
    for (int j = 0; j < 4; ++j) {
      k32[i][j] = fkey32(acc[i][j]);
      atomicAdd(&sm.h.lh[k32[i][j] >> 20], 1);
    }
  __syncthreads();
  const int BPT = BIN12 / 256;              // 16 bins/thread
  int base = t * BPT;
  int lsum = 0;
  for (int j = 0; j < BPT; ++j) lsum += sm.h.lh[base + j];
  sm.h.part[t] = lsum;
  __syncthreads();
  for (int off = 1; off < 256; off <<= 1) { // suffix scan over 256 partials
    int v = (t + off < 256) ? sm.h.part[t + off] : 0;
    __syncthreads();
    sm.h.part[t] += v;
    __syncthreads();
  }
  int Sab = sm.h.part[t] - lsum;            // count strictly above my bin range
  if (Sab < KM && Sab + lsum >= KM) {       // unique crossing thread
    int c = Sab;
    for (int j = BPT - 1; j >= 0; --j) {
      c += sm.h.lh[base + j];
      if (c >= KM) { Bbin = base + j; break; }
    }
  }
  __syncthreads();
  int Bb = Bbin;
  for (int i = 0; i < 4; ++i)
    for (int j = 0; j < 4; ++j)
      if ((int)(k32[i][j] >> 20) >= Bb) {
        int pos = atomicAdd(&lcnt, 1);      // <= 4096 always
        int flat = (row0 + ra + i) * KKP + (col0 + rb + j);
        sm.h.lbuf[pos] = ((u64)k32[i][j] << 32) | (u32)(~(u32)flat);
      }
  __syncthreads();
  if (t == 0) gbase = atomicAdd(&mcnt[b * 16], lcnt);   // ONE global atomic/block
  __syncthreads();
  int n = lcnt, g0 = gbase;
  for (int i = t; i < n; i += 256) {
    int g = g0 + i;
    if (g < CAP_MC) mcand[(size_t)b * CAP_MC + g] = sm.h.lbuf[i];
  }
}

// ---------------- exact match top-128 from per-block candidates ----------------
// grid=2 (one block/batch). Radix-select over ~9K candidate keys (same proven
// pattern as kp_select), adaptive bitonic, decode to locations.
__global__ __launch_bounds__(1024) void match_select(const u64* __restrict__ mcand,
                                                     const int* __restrict__ mcnt,
                                                     const float* __restrict__ kp_loc,
                                                     float* __restrict__ out) {
  __shared__ int hist[NBINS];
  __shared__ u64 kbuf[CAP_COL];
  __shared__ int part[1024];
  __shared__ int Bbin, colcnt;
  int b = blockIdx.x;
  int t = threadIdx.x;
  const u64* keys = mcand + (size_t)b * CAP_MC;
  int n = mcnt[b * 16]; if (n > CAP_MC) n = CAP_MC;
  for (int i = t; i < NBINS; i += 1024) hist[i] = 0;
  if (t == 0) { Bbin = 0; colcnt = 0; }
  __syncthreads();
  for (int i = t; i < n; i += 1024) {
    u32 bin = (u32)(keys[i] >> 50);         // key32 >> 18, 14 bits
    atomicAdd(&hist[bin], 1);
  }
  __syncthreads();
  const int BPT = NBINS / 1024;
  int base = t * BPT;
  int lsum = 0;
  for (int j = 0; j < BPT; ++j) lsum += hist[base + j];
  part[t] = lsum;
  __syncthreads();
  for (int off = 1; off < 1024; off <<= 1) {   // suffix scan
    int v = (t + off < 1024) ? part[t + off] : 0;
    __syncthreads();
    part[t] += v;
    __syncthreads();
  }
  int Sab = part[t] - lsum;
  if (Sab < KM && Sab + lsum >= KM) {
    int c = Sab;
    for (int j = BPT - 1; j >= 0; --j) {
      c += hist[base + j];
      if (c >= KM) { Bbin = base + j; break; }
    }
  }
  __syncthreads();
  int Bb = Bbin;
  for (int i = t; i < n; i += 1024) {
    u64 kk = keys[i];
    if ((int)(kk >> 50) >= Bb) {
      int pos = atomicAdd(&colcnt, 1);
      if (pos < CAP_COL) kbuf[pos] = kk;
    }
  }
  __syncthreads();
  int nc = colcnt; if (nc > CAP_COL) nc = CAP_COL;   // nc >= 128 by construction
  int need = nc > KM ? nc : KM;
  int npow = 1; while (npow < need) npow <<= 1;
  for (int i = t; i < npow; i += 1024) if (i >= nc) kbuf[i] = 0;
  __syncthreads();
  bitonicN(kbuf, t, npow, 1024);
  if (t < KM) {
    u64 key = kbuf[t];
    u32 flat = ~(u32)key;
    int i1 = (int)(flat >> 9), i2 = (int)(flat & 511);
    if (i1 >= KKP) { i1 = 0; i2 = 0; }  // pad guard
    int slot1 = b, slot2 = 2 + b;
    out[(b * 4 + 0) * KM + t] = kp_loc[(slot1 * 2 + 0) * KKP + i1];
    out[(b * 4 + 1) * KM + t] = kp_loc[(slot1 * 2 + 1) * KKP + i1];
    out[(b * 4 + 2) * KM + t] = kp_loc[(slot2 * 2 + 0) * KKP + i2];
    out[(b * 4 + 3) * KM + t] = kp_loc[(slot2 * 2 + 1) * KKP + i2];
  }
}

extern "C" void kernel_launch(void* const* d_in, const int* in_sizes, int n_in,
                              void* d_out, int out_size, void* d_ws, size_t ws_size,
                              hipStream_t stream) {
  (void)in_sizes; (void)n_in; (void)out_size; (void)ws_size;
  InPtrs P;
  P.rep[0][0] = (const float*)d_in[0];  P.rel[0][0] = (const float*)d_in[1];  P.desc[0][0] = (const float*)d_in[2];
  P.rep[0][1] = (const float*)d_in[3];  P.rel[0][1] = (const float*)d_in[4];  P.desc[0][1] = (const float*)d_in[5];
  P.rep[1][0] = (const float*)d_in[6];  P.rel[1][0] = (const float*)d_in[7];  P.desc[1][0] = (const float*)d_in[8];
  P.rep[1][1] = (const float*)d_in[9];  P.rel[1][1] = (const float*)d_in[10]; P.desc[1][1] = (const float*)d_in[11];

  char* ws = (char*)d_ws;
  // counters: each slot's counter on its own 64B cacheline (stride-16 ints)
  int*   cnt_cand = (int*)(ws + 0);       // cnt_cand[slot*16], 4 slots
  int*   mcnt     = (int*)(ws + 256);     // mcnt[b*16], 2 batches
  size_t off = 1024;
  u64*   cand    = (u64*)(ws + off);  off += 4ULL * CAP_CAND * 8;
  float* kp_loc  = (float*)(ws + off); off += 4ULL * 2 * KKP * 4;
  int*   kp_level= (int*)(ws + off);  off += 4ULL * KKP * 4;
  int*   kp_p    = (int*)(ws + off);  off += 4ULL * KKP * 4;
  float* kp_score= (float*)(ws + off); off += 4ULL * KKP * 4;
  float* dAt     = (float*)(ws + off); off += 4ULL * KKP * 128 * 4;
  u64*   mcand   = (u64*)(ws + off);  off += 2ULL * CAP_MC * 8;   // ~2.1 MB total

  // zero counters only
  hipMemsetAsync(d_ws, 0, 1024, stream);

  cand_kernel<<<dim3(NTOT / 256, 4), 256, 0, stream>>>(P, cand, cnt_cand);
  kp_select<<<4, 1024, 0, stream>>>(cand, cnt_cand, kp_loc, kp_level, kp_p, kp_score);
  gather_kernel<<<dim3(128, 4), 512, 0, stream>>>(P, kp_level, kp_p, kp_score, dAt);
  gemm_kernel<<<dim3(8, 8, 2), dim3(16, 16), 0, stream>>>(dAt, mcand, mcnt);
  match_select<<<2, 1024, 0, stream>>>(mcand, mcnt, kp_loc, (float*)d_out);
}